// Round 6
// baseline (435.142 us; speedup 1.0000x reference)
//
#include <hip/hip_runtime.h>

#define B_   2
#define S_   2048
#define D_   1024
#define H_   16
#define DK_  64
#define DFF_ 4096
#define NTOK (B_ * S_)   // 4096

#define QSCALE 0.18033688011112042f   // 0.125 * log2(e)

typedef __bf16 bf16x8 __attribute__((ext_vector_type(8)));
typedef __bf16 bf16x4 __attribute__((ext_vector_type(4)));
typedef float  f32x4  __attribute__((ext_vector_type(4)));

#if __has_builtin(__builtin_amdgcn_exp2f)
#define EXP2(x) __builtin_amdgcn_exp2f(x)
#else
#define EXP2(x) exp2f(x)
#endif

// async global->LDS 16B copy. LDS dest is wave-uniform base + lane*16.
__device__ __forceinline__ void ld16(const __bf16* g, __bf16* l) {
  __builtin_amdgcn_global_load_lds(
      (const __attribute__((address_space(1))) void*)g,
      (__attribute__((address_space(3))) void*)l, 16, 0, 0);
}

// ---------------------------------------------------------------------------
// XCD-aware block swizzle (R5). XCD = flat % 8; compact C-patch per XCD.
// ---------------------------------------------------------------------------
__device__ __forceinline__ void xcd_swizzle(int& bx, int& by) {
  const int gx = gridDim.x;
  const int flat = blockIdx.y * gx + blockIdx.x;
  const int x = flat & 7;
  const int n = flat >> 3;
  if (gx == 32) {
    const int px = (x & 1) << 4, py = (x >> 1) << 3;
    const int g = n >> 5, rem = n & 31;
    bx = px + (g << 2) + (rem & 3);
    by = py + (rem >> 2);
  } else {
    const int g = n >> 4, rem = n & 15;
    bx = (g << 2) + (rem & 3);
    by = (x << 2) + (rem >> 2);
  }
}

// ---------------------------------------------------------------------------
// GEMM core, BK=64 (R5): 32 MFMA per barrier. Interleaved-k LDS layout,
// conflict-free b128 frag reads, staging 64B-coalesced. 32 KB LDS.
// ---------------------------------------------------------------------------
__device__ __forceinline__ void gemm_core_128(
    const __bf16* __restrict__ A, const __bf16* __restrict__ W,
    int ld, int kLen, int rowA0, int rowW0,
    f32x4 (&acc)[4][4], __bf16* As, __bf16* Bs)
{
  const int t    = threadIdx.x;
  const int lane = t & 63;
  const int wv   = t >> 6;
  const int wm   = (wv >> 1) << 6;
  const int wn   = (wv & 1) << 6;
  const int l15  = lane & 15;
  const int q4   = lane >> 4;

#pragma unroll
  for (int i = 0; i < 4; ++i)
#pragma unroll
    for (int j = 0; j < 4; ++j)
      acc[i][j] = (f32x4){0.f, 0.f, 0.f, 0.f};

  const __bf16* gA = A + (size_t)(rowA0 + 32 * wv + l15) * ld + q4 * 8;
  const __bf16* gW = W + (size_t)(rowW0 + 32 * wv + l15) * ld + q4 * 8;
  __bf16* lA = As + wv * 2048;
  __bf16* lB = Bs + wv * 2048;
  const size_t r16 = (size_t)16 * ld;

  const int fbg = (q4 << 7) + (l15 << 3);
  const int ia = (wm >> 4);
  const int ib = (wn >> 4);

  for (int k0 = 0; k0 < kLen; k0 += 64) {
    ld16(gA + k0,            lA);
    ld16(gA + k0 + 32,       lA + 512);
    ld16(gA + k0 + r16,      lA + 1024);
    ld16(gA + k0 + r16 + 32, lA + 1536);
    ld16(gW + k0,            lB);
    ld16(gW + k0 + 32,       lB + 512);
    ld16(gW + k0 + r16,      lB + 1024);
    ld16(gW + k0 + r16 + 32, lB + 1536);
    __syncthreads();
#pragma unroll
    for (int s = 0; s < 2; ++s) {
      bf16x8 af[4], bw[4];
#pragma unroll
      for (int i = 0; i < 4; ++i)
        af[i] = *(const bf16x8*)(As + (ia + i) * 1024 + s * 512 + fbg);
#pragma unroll
      for (int j = 0; j < 4; ++j)
        bw[j] = *(const bf16x8*)(Bs + (ib + j) * 1024 + s * 512 + fbg);
#pragma unroll
      for (int i = 0; i < 4; ++i)
#pragma unroll
        for (int j = 0; j < 4; ++j)
          acc[i][j] = __builtin_amdgcn_mfma_f32_16x16x32_bf16(af[i], bw[j], acc[i][j], 0, 0, 0);
    }
    __syncthreads();
  }
}

// ---------------------------------------------------------------------------
// QKV: grid.z selects {Q,K,V}. Q pre-scaled; V stored transposed vt[b,h,d,s].
// ---------------------------------------------------------------------------
__global__ __launch_bounds__(256) void gemm_qkv(
    const __bf16* __restrict__ xn,
    const __bf16* __restrict__ wqb, const __bf16* __restrict__ wkb,
    const __bf16* __restrict__ wvb,
    __bf16* __restrict__ qo, __bf16* __restrict__ ko, __bf16* __restrict__ vto)
{
  __shared__ __align__(16) __bf16 As[128 * 64];
  __shared__ __align__(16) __bf16 Bs[128 * 64];
  int bx, by; xcd_swizzle(bx, by);
  const __bf16* W = blockIdx.z == 0 ? wqb : (blockIdx.z == 1 ? wkb : wvb);
  f32x4 acc[4][4];
  gemm_core_128(xn, W, D_, D_, by * 128, bx * 128, acc, As, Bs);

  const int t = threadIdx.x, lane = t & 63, wv = t >> 6;
  const int wm = (wv >> 1) << 6, wn = (wv & 1) << 6;
  const int l15 = lane & 15, q4 = lane >> 4;
  const int row0 = by * 128 + wm;
  const int col0 = bx * 128 + wn;

  if (blockIdx.z < 2) {
    __bf16* o = blockIdx.z == 0 ? qo : ko;
    const float sc = blockIdx.z == 0 ? QSCALE : 1.0f;
#pragma unroll
    for (int i = 0; i < 4; ++i)
#pragma unroll
      for (int j = 0; j < 4; ++j)
#pragma unroll
        for (int r = 0; r < 4; ++r) {
          int row = row0 + 16 * i + q4 * 4 + r;
          int col = col0 + 16 * j + l15;
          o[(size_t)row * D_ + col] = (__bf16)(acc[i][j][r] * sc);
        }
  } else {
#pragma unroll
    for (int i = 0; i < 4; ++i)
#pragma unroll
      for (int j = 0; j < 4; ++j) {
        int tok0 = row0 + 16 * i + q4 * 4;
        int c    = col0 + 16 * j + l15;
        int b0 = tok0 >> 11, s0 = tok0 & (S_ - 1);
        int hh = c >> 6, dd = c & (DK_ - 1);
        bf16x4 pk;
#pragma unroll
        for (int r = 0; r < 4; ++r) pk[r] = (__bf16)acc[i][j][r];
        *(bf16x4*)&vto[(size_t)((b0 * H_ + hh) * DK_ + dd) * S_ + s0] = pk;
      }
  }
}

// ---------------------------------------------------------------------------
// FFN1 GEMM: h = relu(A @ W^T + bias) -> bf16.
// ---------------------------------------------------------------------------
__global__ __launch_bounds__(256) void gemm_ffn1(
    const __bf16* __restrict__ A, const __bf16* __restrict__ W,
    __bf16* __restrict__ outb, const float* __restrict__ bias)
{
  __shared__ __align__(16) __bf16 As[128 * 64];
  __shared__ __align__(16) __bf16 Bs[128 * 64];
  int bx, by; xcd_swizzle(bx, by);
  f32x4 acc[4][4];
  gemm_core_128(A, W, D_, D_, by * 128, bx * 128, acc, As, Bs);

  const int t = threadIdx.x, lane = t & 63, wv = t >> 6;
  const int wm = (wv >> 1) << 6, wn = (wv & 1) << 6;
  const int l15 = lane & 15, q4 = lane >> 4;
  const int row0 = by * 128 + wm;
  const int col0 = bx * 128 + wn;

#pragma unroll
  for (int i = 0; i < 4; ++i)
#pragma unroll
    for (int j = 0; j < 4; ++j) {
      int col = col0 + 16 * j + l15;
      float bs = bias[col];
#pragma unroll
      for (int r = 0; r < 4; ++r) {
        int row = row0 + 16 * i + q4 * 4 + r;
        float v = fmaxf(acc[i][j][r] + bs, 0.0f);
        outb[(size_t)row * DFF_ + col] = (__bf16)v;
      }
    }
}

// ---------------------------------------------------------------------------
// split-K GEMM partials (N = 1024). grid (8, 32, 2).
// ---------------------------------------------------------------------------
__global__ __launch_bounds__(256) void gemm_splitk_f32(
    const __bf16* __restrict__ A, const __bf16* __restrict__ W,
    int K, int kPart, float* __restrict__ pp)
{
  __shared__ __align__(16) __bf16 As[128 * 64];
  __shared__ __align__(16) __bf16 Bs[128 * 64];
  int bx, by; xcd_swizzle(bx, by);
  f32x4 acc[4][4];
  const int z = blockIdx.z;
  gemm_core_128(A + (size_t)z * kPart, W + (size_t)z * kPart, K, kPart,
                by * 128, bx * 128, acc, As, Bs);

  const int t = threadIdx.x, lane = t & 63, wv = t >> 6;
  const int wm = (wv >> 1) << 6, wn = (wv & 1) << 6;
  const int l15 = lane & 15, q4 = lane >> 4;
  const int row0 = by * 128 + wm;
  const int col0 = bx * 128 + wn;
  float* out = pp + (size_t)z * NTOK * D_;

#pragma unroll
  for (int i = 0; i < 4; ++i)
#pragma unroll
    for (int j = 0; j < 4; ++j)
#pragma unroll
      for (int r = 0; r < 4; ++r) {
        int row = row0 + 16 * i + q4 * 4 + r;
        int col = col0 + 16 * j + l15;
        out[(size_t)row * D_ + col] = acc[i][j][r];
      }
}

__global__ __launch_bounds__(256) void gemm_splitk_bf16(
    const __bf16* __restrict__ A, const __bf16* __restrict__ W,
    int K, int kPart, __bf16* __restrict__ pp)
{
  __shared__ __align__(16) __bf16 As[128 * 64];
  __shared__ __align__(16) __bf16 Bs[128 * 64];
  int bx, by; xcd_swizzle(bx, by);
  f32x4 acc[4][4];
  const int z = blockIdx.z;
  gemm_core_128(A + (size_t)z * kPart, W + (size_t)z * kPart, K, kPart,
                by * 128, bx * 128, acc, As, Bs);

  const int t = threadIdx.x, lane = t & 63, wv = t >> 6;
  const int wm = (wv >> 1) << 6, wn = (wv & 1) << 6;
  const int l15 = lane & 15, q4 = lane >> 4;
  const int row0 = by * 128 + wm;
  const int col0 = bx * 128 + wn;
  __bf16* out = pp + (size_t)z * NTOK * D_;

#pragma unroll
  for (int i = 0; i < 4; ++i)
#pragma unroll
    for (int j = 0; j < 4; ++j)
#pragma unroll
      for (int r = 0; r < 4; ++r) {
        int row = row0 + 16 * i + q4 * 4 + r;
        int col = col0 + 16 * j + l15;
        out[(size_t)row * D_ + col] = (__bf16)acc[i][j][r];
      }
}

// ---------------------------------------------------------------------------
// O-proj reduce + LN2 fused: x1 = x + p0 + p1; xn2 = LN(x1). 1 block/row.
// ---------------------------------------------------------------------------
__global__ __launch_bounds__(256) void oproj_ln_reduce(
    const float* __restrict__ x, const float* __restrict__ p0,
    const float* __restrict__ p1, const float* __restrict__ alpha,
    const float* __restrict__ bias, float* __restrict__ x1,
    __bf16* __restrict__ xn2)
{
  const int row = blockIdx.x;
  const int t = threadIdx.x;
  const size_t base = (size_t)row * D_;
  float4 v  = ((const float4*)(x  + base))[t];
  const float4 a0 = ((const float4*)(p0 + base))[t];
  const float4 a1 = ((const float4*)(p1 + base))[t];
  v.x += a0.x + a1.x; v.y += a0.y + a1.y;
  v.z += a0.z + a1.z; v.w += a0.w + a1.w;
  ((float4*)(x1 + base))[t] = v;

  float s  = v.x + v.y + v.z + v.w;
  float ss = v.x * v.x + v.y * v.y + v.z * v.z + v.w * v.w;
#pragma unroll
  for (int m = 1; m < 64; m <<= 1) {
    s  += __shfl_xor(s, m);
    ss += __shfl_xor(ss, m);
  }
  __shared__ float red[8];
  if ((t & 63) == 0) { red[t >> 6] = s; red[4 + (t >> 6)] = ss; }
  __syncthreads();
  s  = red[0] + red[1] + red[2] + red[3];
  ss = red[4] + red[5] + red[6] + red[7];
  const float mean = s * (1.0f / D_);
  float var = (ss - (float)D_ * mean * mean) * (1.0f / (D_ - 1));
  var = fmaxf(var, 0.0f);
  const float inv = 1.0f / (sqrtf(var) + 1e-6f);
  const float4 al = ((const float4*)alpha)[t];
  const float4 bi = ((const float4*)bias)[t];
  bf16x4 o;
  o.x = (__bf16)(al.x * (v.x - mean) * inv + bi.x);
  o.y = (__bf16)(al.y * (v.y - mean) * inv + bi.y);
  o.z = (__bf16)(al.z * (v.z - mean) * inv + bi.z);
  o.w = (__bf16)(al.w * (v.w - mean) * inv + bi.w);
  ((bf16x4*)(xn2 + base))[t] = o;
}

// ---------------------------------------------------------------------------
// FFN2 reduce: out = x1 + b2 + p0 + p1 (bf16 partials). 4 f32/thread.
// ---------------------------------------------------------------------------
__global__ __launch_bounds__(256) void ffn2_reduce(
    const float* __restrict__ x1, const __bf16* __restrict__ p0,
    const __bf16* __restrict__ p1, const float* __restrict__ b2,
    float* __restrict__ out)
{
  const int idx4 = blockIdx.x * 256 + threadIdx.x;
  float4 v = ((const float4*)x1)[idx4];
  const float4 bs = ((const float4*)b2)[idx4 & 255];
  const bf16x4 q0 = ((const bf16x4*)p0)[idx4];
  const bf16x4 q1 = ((const bf16x4*)p1)[idx4];
  v.x += bs.x + (float)q0[0] + (float)q1[0];
  v.y += bs.y + (float)q0[1] + (float)q1[1];
  v.z += bs.z + (float)q0[2] + (float)q1[2];
  v.w += bs.w + (float)q0[3] + (float)q1[3];
  ((float4*)out)[idx4] = v;
}

// ---------------------------------------------------------------------------
// weight f32->bf16 casts (jobs 0-5) + fused LN1 (job 6) in one launch.
// ---------------------------------------------------------------------------
struct CastJobs {
  const float* src[6];
  __bf16* dst[6];
  int n4[6];
};

__global__ __launch_bounds__(256) void cast_ln_kernel(
    CastJobs cj, const float* __restrict__ x, const float* __restrict__ alpha,
    const float* __restrict__ bias, __bf16* __restrict__ xn1)
{
  const int j = blockIdx.y;
  if (j < 6) {
    const int i = blockIdx.x * 256 + threadIdx.x;
    if (i < cj.n4[j]) {
      float4 v = ((const float4*)cj.src[j])[i];
      bf16x4 o;
      o.x = (__bf16)v.x; o.y = (__bf16)v.y; o.z = (__bf16)v.z; o.w = (__bf16)v.w;
      ((bf16x4*)cj.dst[j])[i] = o;
    }
    return;
  }
  const int row = blockIdx.x;
  const int t = threadIdx.x;
  const float4 v = ((const float4*)(x + (size_t)row * D_))[t];
  float s  = v.x + v.y + v.z + v.w;
  float ss = v.x * v.x + v.y * v.y + v.z * v.z + v.w * v.w;
#pragma unroll
  for (int m = 1; m < 64; m <<= 1) {
    s  += __shfl_xor(s, m);
    ss += __shfl_xor(ss, m);
  }
  __shared__ float red[8];
  if ((t & 63) == 0) { red[t >> 6] = s; red[4 + (t >> 6)] = ss; }
  __syncthreads();
  s  = red[0] + red[1] + red[2] + red[3];
  ss = red[4] + red[5] + red[6] + red[7];
  const float mean = s * (1.0f / D_);
  float var = (ss - (float)D_ * mean * mean) * (1.0f / (D_ - 1));
  var = fmaxf(var, 0.0f);
  const float inv = 1.0f / (sqrtf(var) + 1e-6f);
  const float4 al = ((const float4*)alpha)[t];
  const float4 bi = ((const float4*)bias)[t];
  bf16x4 o;
  o.x = (__bf16)(al.x * (v.x - mean) * inv + bi.x);
  o.y = (__bf16)(al.y * (v.y - mean) * inv + bi.y);
  o.z = (__bf16)(al.z * (v.z - mean) * inv + bi.z);
  o.w = (__bf16)(al.w * (v.w - mean) * inv + bi.w);
  ((bf16x4*)(xn1 + (size_t)row * D_))[t] = o;
}

// ---------------------------------------------------------------------------
// flash attention with PING-PONG K/V prefetch. BQ=64, BKV=64.
// One barrier per kv-iter: barrier -> issue loads for tile n+1 into the
// alternate buffer -> compute tile n. The compiler's vmcnt(0)-before-barrier
// drains loads that have had a full iteration in flight (true prefetch).
// Q staging is wave-local (wave w stages+reads only rows 16w..16w+16) and is
// overlaid on Ps (read into regs before the first Ps write) -> LDS 41 KB,
// 3 blocks/CU. l-reduction shuffles deferred out of the loop.
// ---------------------------------------------------------------------------
__global__ __launch_bounds__(256) void attn_kernel(
    const __bf16* __restrict__ qg, const __bf16* __restrict__ kg,
    const __bf16* __restrict__ vtg, const int* __restrict__ mask,
    __bf16* __restrict__ av)
{
  __shared__ __align__(16) __bf16 Ks[2][64 * 64];   // 2 x 8 KB
  __shared__ __align__(16) __bf16 Vt[2][64 * 64];   // 2 x 8 KB
  __shared__ __align__(16) __bf16 Ps[64 * 72];      // 9 KB; rows 16w.. are
                                                    // wave-local; Q overlaid
  const int t = threadIdx.x, lane = t & 63, wv = t >> 6;
  const int l15 = lane & 15, q4 = lane >> 4;
  const int bh = blockIdx.x;
  const int b = bh >> 4, h = bh & (H_ - 1);
  const int q0 = blockIdx.y * 64;

  const int srow = lane & 7, sc8 = lane >> 3;
  const __bf16* qg0 = qg + (size_t)(b * S_ + q0 + 16 * wv + srow) * D_ + h * DK_ + sc8 * 8;
  const __bf16* kg0 = kg + (size_t)(b * S_ + 16 * wv + srow) * D_ + h * DK_ + sc8 * 8;
  const __bf16* vt0 = vtg + (size_t)(bh * DK_ + 16 * wv + srow) * S_ + sc8 * 8;

  // Q -> wave-private slice of Ps (rows 16wv..16wv+15 = 1152 elems, 16B-align)
  __bf16* lQ = Ps + wv * 1152;
  ld16(qg0, lQ);
  ld16(qg0 + (size_t)8 * D_, lQ + 512);

  // stage K/V tile 0 into buffer 0
  ld16(kg0,                  &Ks[0][wv * 1024]);
  ld16(kg0 + (size_t)8 * D_, &Ks[0][wv * 1024 + 512]);
  ld16(vt0,                  &Vt[0][wv * 1024]);
  ld16(vt0 + (size_t)8 * S_, &Vt[0][wv * 1024 + 512]);

  const int fb = ((l15 >> 3) << 9) + (q4 << 6) + ((l15 & 7) << 3);
  const int mrow = b * S_;

  float lsum = 0.0f;
  f32x4 oacc[4];
#pragma unroll
  for (int jd = 0; jd < 4; ++jd) oacc[jd] = (f32x4){0.f, 0.f, 0.f, 0.f};
  bf16x8 bq[2];

  for (int n = 0; n < S_ / 64; ++n) {
    const int cur = n & 1;
    const int kvc = n << 6;
    __syncthreads();   // tile n staging (issued last iter) is complete

    // prefetch tile n+1 into the alternate buffer (tile 0 re-load on last
    // iter keeps the loop branch-free; it is never consumed)
    {
      const int kvn = (n < S_ / 64 - 1) ? (kvc + 64) : 0;
      __bf16* nk = &Ks[cur ^ 1][wv * 1024];
      __bf16* nv = &Vt[cur ^ 1][wv * 1024];
      ld16(kg0 + (size_t)kvn * D_,       nk);
      ld16(kg0 + (size_t)(kvn + 8) * D_, nk + 512);
      ld16(vt0 + kvn,                    nv);
      ld16(vt0 + (size_t)8 * S_ + kvn,   nv + 512);
    }

    if (n == 0) {   // read Q frags from the wave-private overlay, then Ps owns it
      bq[0] = *(const bf16x8*)(lQ + fb);
      bq[1] = *(const bf16x8*)(lQ + fb + 256);
    }

    const int mv = mask[mrow + kvc + lane];
    const bool dirty = (__ballot(mv == 0) != 0ull);

    // S^T = K Q^T
    f32x4 sacc[4];
#pragma unroll
    for (int i = 0; i < 4; ++i) sacc[i] = (f32x4){0.f, 0.f, 0.f, 0.f};
#pragma unroll
    for (int i = 0; i < 4; ++i)
#pragma unroll
      for (int s = 0; s < 2; ++s) {
        bf16x8 ak = *(const bf16x8*)(&Ks[cur][i * 1024 + fb + s * 256]);
        sacc[i] = __builtin_amdgcn_mfma_f32_16x16x32_bf16(ak, bq[s], sacc[i], 0, 0, 0);
      }

    if (dirty) {   // cold path (all-ones mask never takes it)
#pragma unroll
      for (int i = 0; i < 4; ++i)
#pragma unroll
        for (int r = 0; r < 4; ++r)
          if (mask[mrow + kvc + 16 * i + 4 * q4 + r] == 0) sacc[i][r] = -1e30f;
    }

    // fixed-max softmax; P -> Ps (wave-local rows); l-sum stays per-lane
    float rsum = 0.0f;
#pragma unroll
    for (int i = 0; i < 4; ++i) {
      bf16x4 pb;
#pragma unroll
      for (int r = 0; r < 4; ++r) {
        float pp = EXP2(sacc[i][r]);
        rsum += pp;
        pb[r] = (__bf16)pp;
      }
      *(bf16x4*)(Ps + (wv * 16 + l15) * 72 + 16 * i + q4 * 4) = pb;
    }
    lsum += rsum;

    // O += P V
    bf16x8 ap[2];
#pragma unroll
    for (int s = 0; s < 2; ++s)
      ap[s] = *(const bf16x8*)(Ps + (wv * 16 + l15) * 72 + s * 32 + q4 * 8);
#pragma unroll
    for (int jd = 0; jd < 4; ++jd)
#pragma unroll
      for (int s = 0; s < 2; ++s) {
        bf16x8 bv = *(const bf16x8*)(&Vt[cur][jd * 1024 + fb + s * 256]);
        oacc[jd] = __builtin_amdgcn_mfma_f32_16x16x32_bf16(ap[s], bv, oacc[jd], 0, 0, 0);
      }
    // no end-of-iter barrier: next iter's barrier protects buffer reuse
  }

  // deferred l reduction (sum over q4 lane groups), transpose, store
  lsum += __shfl_xor(lsum, 16);
  lsum += __shfl_xor(lsum, 32);
  float lt[4];
#pragma unroll
  for (int r = 0; r < 4; ++r) lt[r] = 1.0f / __shfl(lsum, q4 * 4 + r);
#pragma unroll
  for (int jd = 0; jd < 4; ++jd)
#pragma unroll
    for (int r = 0; r < 4; ++r) {
      int tok = b * S_ + q0 + wv * 16 + q4 * 4 + r;
      int c   = h * DK_ + jd * 16 + l15;
      av[(size_t)tok * D_ + c] = (__bf16)(oacc[jd][r] * lt[r]);
    }
}

// ---------------------------------------------------------------------------
extern "C" void kernel_launch(void* const* d_in, const int* in_sizes, int n_in,
                              void* d_out, int out_size, void* d_ws, size_t ws_size,
                              hipStream_t stream) {
  const float* x      = (const float*)d_in[0];
  const int*   mask   = (const int*)d_in[1];
  const float* wq     = (const float*)d_in[2];
  const float* wk     = (const float*)d_in[3];
  const float* wv     = (const float*)d_in[4];
  const float* wo     = (const float*)d_in[5];
  const float* w1     = (const float*)d_in[6];
  const float* b1     = (const float*)d_in[7];
  const float* w2     = (const float*)d_in[8];
  const float* b2     = (const float*)d_in[9];
  const float* alpha1 = (const float*)d_in[10];
  const float* bias1  = (const float*)d_in[11];
  const float* alpha2 = (const float*)d_in[12];
  const float* bias2  = (const float*)d_in[13];

  char* ws = (char*)d_ws;
  __bf16* wqb = (__bf16*)(ws + ((size_t)0 << 20));
  __bf16* wkb = (__bf16*)(ws + ((size_t)2 << 20));
  __bf16* wvb = (__bf16*)(ws + ((size_t)4 << 20));
  __bf16* wob = (__bf16*)(ws + ((size_t)6 << 20));
  __bf16* w1b = (__bf16*)(ws + ((size_t)8 << 20));
  __bf16* w2b = (__bf16*)(ws + ((size_t)16 << 20));
  __bf16* xn1 = (__bf16*)(ws + ((size_t)24 << 20));
  __bf16* qb  = (__bf16*)(ws + ((size_t)32 << 20));
  __bf16* kb  = (__bf16*)(ws + ((size_t)40 << 20));
  __bf16* vtb = (__bf16*)(ws + ((size_t)48 << 20));
  __bf16* avb = (__bf16*)(ws + ((size_t)56 << 20));
  float*  x1  = (float*) (ws + ((size_t)64 << 20));
  __bf16* xn2 = (__bf16*)(ws + ((size_t)56 << 20));
  __bf16* hb  = (__bf16*)(ws + ((size_t)24 << 20));
  float*  op0 = (float*) (ws + ((size_t)24 << 20));
  float*  op1 = (float*) (ws + ((size_t)40 << 20));
  __bf16* fp0 = (__bf16*)(ws + ((size_t)0 << 20));
  __bf16* fp1 = (__bf16*)(ws + ((size_t)8 << 20));

  CastJobs cj;
  cj.src[0] = wq; cj.dst[0] = wqb; cj.n4[0] = D_ * D_ / 4;
  cj.src[1] = wk; cj.dst[1] = wkb; cj.n4[1] = D_ * D_ / 4;
  cj.src[2] = wv; cj.dst[2] = wvb; cj.n4[2] = D_ * D_ / 4;
  cj.src[3] = wo; cj.dst[3] = wob; cj.n4[3] = D_ * D_ / 4;
  cj.src[4] = w1; cj.dst[4] = w1b; cj.n4[4] = DFF_ * D_ / 4;
  cj.src[5] = w2; cj.dst[5] = w2b; cj.n4[5] = DFF_ * D_ / 4;

  cast_ln_kernel<<<dim3(DFF_ * D_ / 4 / 256, 7), 256, 0, stream>>>(
      cj, x, alpha1, bias1, xn1);

  gemm_qkv<<<dim3(D_ / 128, NTOK / 128, 3), 256, 0, stream>>>(
      xn1, wqb, wkb, wvb, qb, kb, vtb);

  attn_kernel<<<dim3(B_ * H_, S_ / 64), 256, 0, stream>>>(qb, kb, vtb, mask, avb);

  gemm_splitk_f32<<<dim3(D_ / 128, NTOK / 128, 2), 256, 0, stream>>>(
      avb, wob, D_, D_ / 2, op0);

  oproj_ln_reduce<<<dim3(NTOK), 256, 0, stream>>>(
      x, op0, op1, alpha2, bias2, x1, xn2);

  gemm_ffn1<<<dim3(DFF_ / 128, NTOK / 128), 256, 0, stream>>>(
      xn2, w1b, hb, b1);

  gemm_splitk_bf16<<<dim3(D_ / 128, NTOK / 128, 2), 256, 0, stream>>>(
      hb, w2b, DFF_, DFF_ / 2, fp0);

  ffn2_reduce<<<dim3(NTOK * D_ / 4 / 256), 256, 0, stream>>>(
      x1, fp0, fp1, b2, (float*)d_out);
}

// Round 7
// 413.045 us; speedup vs baseline: 1.0535x; 1.0535x over previous
//
#include <hip/hip_runtime.h>

#define B_   2
#define S_   2048
#define D_   1024
#define H_   16
#define DK_  64
#define DFF_ 4096
#define NTOK (B_ * S_)   // 4096

#define QSCALE 0.18033688011112042f   // 0.125 * log2(e)

typedef __bf16 bf16x8 __attribute__((ext_vector_type(8)));
typedef __bf16 bf16x4 __attribute__((ext_vector_type(4)));
typedef float  f32x4  __attribute__((ext_vector_type(4)));

#if __has_builtin(__builtin_amdgcn_exp2f)
#define EXP2(x) __builtin_amdgcn_exp2f(x)
#else
#define EXP2(x) exp2f(x)
#endif

// async global->LDS 16B copy. LDS dest is wave-uniform base + lane*16.
__device__ __forceinline__ void ld16(const __bf16* g, __bf16* l) {
  __builtin_amdgcn_global_load_lds(
      (const __attribute__((address_space(1))) void*)g,
      (__attribute__((address_space(3))) void*)l, 16, 0, 0);
}

// ---------------------------------------------------------------------------
// XCD-aware block swizzle (R5). XCD = flat % 8; compact C-patch per XCD.
// ---------------------------------------------------------------------------
__device__ __forceinline__ void xcd_swizzle(int& bx, int& by) {
  const int gx = gridDim.x;
  const int flat = blockIdx.y * gx + blockIdx.x;
  const int x = flat & 7;
  const int n = flat >> 3;
  if (gx == 32) {
    const int px = (x & 1) << 4, py = (x >> 1) << 3;
    const int g = n >> 5, rem = n & 31;
    bx = px + (g << 2) + (rem & 3);
    by = py + (rem >> 2);
  } else {
    const int g = n >> 4, rem = n & 15;
    bx = (g << 2) + (rem & 3);
    by = (x << 2) + (rem >> 2);
  }
}

// ---------------------------------------------------------------------------
// GEMM core, BK=64 (R5): 32 MFMA per barrier. Interleaved-k LDS layout,
// conflict-free b128 frag reads, staging 64B-coalesced. 32 KB LDS.
// ---------------------------------------------------------------------------
__device__ __forceinline__ void gemm_core_128(
    const __bf16* __restrict__ A, const __bf16* __restrict__ W,
    int ld, int kLen, int rowA0, int rowW0,
    f32x4 (&acc)[4][4], __bf16* As, __bf16* Bs)
{
  const int t    = threadIdx.x;
  const int lane = t & 63;
  const int wv   = t >> 6;
  const int wm   = (wv >> 1) << 6;
  const int wn   = (wv & 1) << 6;
  const int l15  = lane & 15;
  const int q4   = lane >> 4;

#pragma unroll
  for (int i = 0; i < 4; ++i)
#pragma unroll
    for (int j = 0; j < 4; ++j)
      acc[i][j] = (f32x4){0.f, 0.f, 0.f, 0.f};

  const __bf16* gA = A + (size_t)(rowA0 + 32 * wv + l15) * ld + q4 * 8;
  const __bf16* gW = W + (size_t)(rowW0 + 32 * wv + l15) * ld + q4 * 8;
  __bf16* lA = As + wv * 2048;
  __bf16* lB = Bs + wv * 2048;
  const size_t r16 = (size_t)16 * ld;

  const int fbg = (q4 << 7) + (l15 << 3);
  const int ia = (wm >> 4);
  const int ib = (wn >> 4);

  for (int k0 = 0; k0 < kLen; k0 += 64) {
    ld16(gA + k0,            lA);
    ld16(gA + k0 + 32,       lA + 512);
    ld16(gA + k0 + r16,      lA + 1024);
    ld16(gA + k0 + r16 + 32, lA + 1536);
    ld16(gW + k0,            lB);
    ld16(gW + k0 + 32,       lB + 512);
    ld16(gW + k0 + r16,      lB + 1024);
    ld16(gW + k0 + r16 + 32, lB + 1536);
    __syncthreads();
#pragma unroll
    for (int s = 0; s < 2; ++s) {
      bf16x8 af[4], bw[4];
#pragma unroll
      for (int i = 0; i < 4; ++i)
        af[i] = *(const bf16x8*)(As + (ia + i) * 1024 + s * 512 + fbg);
#pragma unroll
      for (int j = 0; j < 4; ++j)
        bw[j] = *(const bf16x8*)(Bs + (ib + j) * 1024 + s * 512 + fbg);
#pragma unroll
      for (int i = 0; i < 4; ++i)
#pragma unroll
        for (int j = 0; j < 4; ++j)
          acc[i][j] = __builtin_amdgcn_mfma_f32_16x16x32_bf16(af[i], bw[j], acc[i][j], 0, 0, 0);
    }
    __syncthreads();
  }
}

// ---------------------------------------------------------------------------
// QKV: grid.z selects {Q,K,V}. Q pre-scaled; V stored transposed vt[b,h,d,s].
// ---------------------------------------------------------------------------
__global__ __launch_bounds__(256) void gemm_qkv(
    const __bf16* __restrict__ xn,
    const __bf16* __restrict__ wqb, const __bf16* __restrict__ wkb,
    const __bf16* __restrict__ wvb,
    __bf16* __restrict__ qo, __bf16* __restrict__ ko, __bf16* __restrict__ vto)
{
  __shared__ __align__(16) __bf16 As[128 * 64];
  __shared__ __align__(16) __bf16 Bs[128 * 64];
  int bx, by; xcd_swizzle(bx, by);
  const __bf16* W = blockIdx.z == 0 ? wqb : (blockIdx.z == 1 ? wkb : wvb);
  f32x4 acc[4][4];
  gemm_core_128(xn, W, D_, D_, by * 128, bx * 128, acc, As, Bs);

  const int t = threadIdx.x, lane = t & 63, wv = t >> 6;
  const int wm = (wv >> 1) << 6, wn = (wv & 1) << 6;
  const int l15 = lane & 15, q4 = lane >> 4;
  const int row0 = by * 128 + wm;
  const int col0 = bx * 128 + wn;

  if (blockIdx.z < 2) {
    __bf16* o = blockIdx.z == 0 ? qo : ko;
    const float sc = blockIdx.z == 0 ? QSCALE : 1.0f;
#pragma unroll
    for (int i = 0; i < 4; ++i)
#pragma unroll
      for (int j = 0; j < 4; ++j)
#pragma unroll
        for (int r = 0; r < 4; ++r) {
          int row = row0 + 16 * i + q4 * 4 + r;
          int col = col0 + 16 * j + l15;
          o[(size_t)row * D_ + col] = (__bf16)(acc[i][j][r] * sc);
        }
  } else {
#pragma unroll
    for (int i = 0; i < 4; ++i)
#pragma unroll
      for (int j = 0; j < 4; ++j) {
        int tok0 = row0 + 16 * i + q4 * 4;
        int c    = col0 + 16 * j + l15;
        int b0 = tok0 >> 11, s0 = tok0 & (S_ - 1);
        int hh = c >> 6, dd = c & (DK_ - 1);
        bf16x4 pk;
#pragma unroll
        for (int r = 0; r < 4; ++r) pk[r] = (__bf16)acc[i][j][r];
        *(bf16x4*)&vto[(size_t)((b0 * H_ + hh) * DK_ + dd) * S_ + s0] = pk;
      }
  }
}

// ---------------------------------------------------------------------------
// FFN1 GEMM: h = relu(A @ W^T + bias) -> bf16.
// ---------------------------------------------------------------------------
__global__ __launch_bounds__(256) void gemm_ffn1(
    const __bf16* __restrict__ A, const __bf16* __restrict__ W,
    __bf16* __restrict__ outb, const float* __restrict__ bias)
{
  __shared__ __align__(16) __bf16 As[128 * 64];
  __shared__ __align__(16) __bf16 Bs[128 * 64];
  int bx, by; xcd_swizzle(bx, by);
  f32x4 acc[4][4];
  gemm_core_128(A, W, D_, D_, by * 128, bx * 128, acc, As, Bs);

  const int t = threadIdx.x, lane = t & 63, wv = t >> 6;
  const int wm = (wv >> 1) << 6, wn = (wv & 1) << 6;
  const int l15 = lane & 15, q4 = lane >> 4;
  const int row0 = by * 128 + wm;
  const int col0 = bx * 128 + wn;

#pragma unroll
  for (int i = 0; i < 4; ++i)
#pragma unroll
    for (int j = 0; j < 4; ++j) {
      int col = col0 + 16 * j + l15;
      float bs = bias[col];
#pragma unroll
      for (int r = 0; r < 4; ++r) {
        int row = row0 + 16 * i + q4 * 4 + r;
        float v = fmaxf(acc[i][j][r] + bs, 0.0f);
        outb[(size_t)row * DFF_ + col] = (__bf16)v;
      }
    }
}

// ---------------------------------------------------------------------------
// split-K GEMM partials (N = 1024). grid (8, 32, 2).
// ---------------------------------------------------------------------------
__global__ __launch_bounds__(256) void gemm_splitk_f32(
    const __bf16* __restrict__ A, const __bf16* __restrict__ W,
    int K, int kPart, float* __restrict__ pp)
{
  __shared__ __align__(16) __bf16 As[128 * 64];
  __shared__ __align__(16) __bf16 Bs[128 * 64];
  int bx, by; xcd_swizzle(bx, by);
  f32x4 acc[4][4];
  const int z = blockIdx.z;
  gemm_core_128(A + (size_t)z * kPart, W + (size_t)z * kPart, K, kPart,
                by * 128, bx * 128, acc, As, Bs);

  const int t = threadIdx.x, lane = t & 63, wv = t >> 6;
  const int wm = (wv >> 1) << 6, wn = (wv & 1) << 6;
  const int l15 = lane & 15, q4 = lane >> 4;
  const int row0 = by * 128 + wm;
  const int col0 = bx * 128 + wn;
  float* out = pp + (size_t)z * NTOK * D_;

#pragma unroll
  for (int i = 0; i < 4; ++i)
#pragma unroll
    for (int j = 0; j < 4; ++j)
#pragma unroll
      for (int r = 0; r < 4; ++r) {
        int row = row0 + 16 * i + q4 * 4 + r;
        int col = col0 + 16 * j + l15;
        out[(size_t)row * D_ + col] = acc[i][j][r];
      }
}

__global__ __launch_bounds__(256) void gemm_splitk_bf16(
    const __bf16* __restrict__ A, const __bf16* __restrict__ W,
    int K, int kPart, __bf16* __restrict__ pp)
{
  __shared__ __align__(16) __bf16 As[128 * 64];
  __shared__ __align__(16) __bf16 Bs[128 * 64];
  int bx, by; xcd_swizzle(bx, by);
  f32x4 acc[4][4];
  const int z = blockIdx.z;
  gemm_core_128(A + (size_t)z * kPart, W + (size_t)z * kPart, K, kPart,
                by * 128, bx * 128, acc, As, Bs);

  const int t = threadIdx.x, lane = t & 63, wv = t >> 6;
  const int wm = (wv >> 1) << 6, wn = (wv & 1) << 6;
  const int l15 = lane & 15, q4 = lane >> 4;
  const int row0 = by * 128 + wm;
  const int col0 = bx * 128 + wn;
  __bf16* out = pp + (size_t)z * NTOK * D_;

#pragma unroll
  for (int i = 0; i < 4; ++i)
#pragma unroll
    for (int j = 0; j < 4; ++j)
#pragma unroll
      for (int r = 0; r < 4; ++r) {
        int row = row0 + 16 * i + q4 * 4 + r;
        int col = col0 + 16 * j + l15;
        out[(size_t)row * D_ + col] = (__bf16)acc[i][j][r];
      }
}

// ---------------------------------------------------------------------------
// O-proj reduce + LN2 fused: x1 = x + p0 + p1; xn2 = LN(x1). 1 block/row.
// ---------------------------------------------------------------------------
__global__ __launch_bounds__(256) void oproj_ln_reduce(
    const float* __restrict__ x, const float* __restrict__ p0,
    const float* __restrict__ p1, const float* __restrict__ alpha,
    const float* __restrict__ bias, float* __restrict__ x1,
    __bf16* __restrict__ xn2)
{
  const int row = blockIdx.x;
  const int t = threadIdx.x;
  const size_t base = (size_t)row * D_;
  float4 v  = ((const float4*)(x  + base))[t];
  const float4 a0 = ((const float4*)(p0 + base))[t];
  const float4 a1 = ((const float4*)(p1 + base))[t];
  v.x += a0.x + a1.x; v.y += a0.y + a1.y;
  v.z += a0.z + a1.z; v.w += a0.w + a1.w;
  ((float4*)(x1 + base))[t] = v;

  float s  = v.x + v.y + v.z + v.w;
  float ss = v.x * v.x + v.y * v.y + v.z * v.z + v.w * v.w;
#pragma unroll
  for (int m = 1; m < 64; m <<= 1) {
    s  += __shfl_xor(s, m);
    ss += __shfl_xor(ss, m);
  }
  __shared__ float red[8];
  if ((t & 63) == 0) { red[t >> 6] = s; red[4 + (t >> 6)] = ss; }
  __syncthreads();
  s  = red[0] + red[1] + red[2] + red[3];
  ss = red[4] + red[5] + red[6] + red[7];
  const float mean = s * (1.0f / D_);
  float var = (ss - (float)D_ * mean * mean) * (1.0f / (D_ - 1));
  var = fmaxf(var, 0.0f);
  const float inv = 1.0f / (sqrtf(var) + 1e-6f);
  const float4 al = ((const float4*)alpha)[t];
  const float4 bi = ((const float4*)bias)[t];
  bf16x4 o;
  o.x = (__bf16)(al.x * (v.x - mean) * inv + bi.x);
  o.y = (__bf16)(al.y * (v.y - mean) * inv + bi.y);
  o.z = (__bf16)(al.z * (v.z - mean) * inv + bi.z);
  o.w = (__bf16)(al.w * (v.w - mean) * inv + bi.w);
  ((bf16x4*)(xn2 + base))[t] = o;
}

// ---------------------------------------------------------------------------
// FFN2 reduce: out = x1 + b2 + p0 + p1 (bf16 partials). 4 f32/thread.
// ---------------------------------------------------------------------------
__global__ __launch_bounds__(256) void ffn2_reduce(
    const float* __restrict__ x1, const __bf16* __restrict__ p0,
    const __bf16* __restrict__ p1, const float* __restrict__ b2,
    float* __restrict__ out)
{
  const int idx4 = blockIdx.x * 256 + threadIdx.x;
  float4 v = ((const float4*)x1)[idx4];
  const float4 bs = ((const float4*)b2)[idx4 & 255];
  const bf16x4 q0 = ((const bf16x4*)p0)[idx4];
  const bf16x4 q1 = ((const bf16x4*)p1)[idx4];
  v.x += bs.x + (float)q0[0] + (float)q1[0];
  v.y += bs.y + (float)q0[1] + (float)q1[1];
  v.z += bs.z + (float)q0[2] + (float)q1[2];
  v.w += bs.w + (float)q0[3] + (float)q1[3];
  ((float4*)out)[idx4] = v;
}

// ---------------------------------------------------------------------------
// weight f32->bf16 casts (jobs 0-5) + fused LN1 (job 6) in one launch.
// ---------------------------------------------------------------------------
struct CastJobs {
  const float* src[6];
  __bf16* dst[6];
  int n4[6];
};

__global__ __launch_bounds__(256) void cast_ln_kernel(
    CastJobs cj, const float* __restrict__ x, const float* __restrict__ alpha,
    const float* __restrict__ bias, __bf16* __restrict__ xn1)
{
  const int j = blockIdx.y;
  if (j < 6) {
    const int i = blockIdx.x * 256 + threadIdx.x;
    if (i < cj.n4[j]) {
      float4 v = ((const float4*)cj.src[j])[i];
      bf16x4 o;
      o.x = (__bf16)v.x; o.y = (__bf16)v.y; o.z = (__bf16)v.z; o.w = (__bf16)v.w;
      ((bf16x4*)cj.dst[j])[i] = o;
    }
    return;
  }
  const int row = blockIdx.x;
  const int t = threadIdx.x;
  const float4 v = ((const float4*)(x + (size_t)row * D_))[t];
  float s  = v.x + v.y + v.z + v.w;
  float ss = v.x * v.x + v.y * v.y + v.z * v.z + v.w * v.w;
#pragma unroll
  for (int m = 1; m < 64; m <<= 1) {
    s  += __shfl_xor(s, m);
    ss += __shfl_xor(ss, m);
  }
  __shared__ float red[8];
  if ((t & 63) == 0) { red[t >> 6] = s; red[4 + (t >> 6)] = ss; }
  __syncthreads();
  s  = red[0] + red[1] + red[2] + red[3];
  ss = red[4] + red[5] + red[6] + red[7];
  const float mean = s * (1.0f / D_);
  float var = (ss - (float)D_ * mean * mean) * (1.0f / (D_ - 1));
  var = fmaxf(var, 0.0f);
  const float inv = 1.0f / (sqrtf(var) + 1e-6f);
  const float4 al = ((const float4*)alpha)[t];
  const float4 bi = ((const float4*)bias)[t];
  bf16x4 o;
  o.x = (__bf16)(al.x * (v.x - mean) * inv + bi.x);
  o.y = (__bf16)(al.y * (v.y - mean) * inv + bi.y);
  o.z = (__bf16)(al.z * (v.z - mean) * inv + bi.z);
  o.w = (__bf16)(al.w * (v.w - mean) * inv + bi.w);
  ((bf16x4*)(xn1 + (size_t)row * D_))[t] = o;
}

// ---------------------------------------------------------------------------
// flash attention, BQ=128: wave owns 32 q-cols (2 j-slices), Q B-frags in
// registers -> K/V LDS fragment reads amortize over 2x MFMA (R6 post-mortem:
// LDS data path was ~57% of the iteration). Two-barrier loop (ping-pong was
// neutral, R6). Fixed-max softmax (R4-verified). Q staged into wave-private
// overlay of Ps. LDS = 8K(Ks)+8K(Vt)+18K(Ps) = 34 KB. Grid 512 = 2 blocks/CU.
// ---------------------------------------------------------------------------
__global__ __launch_bounds__(256) void attn_kernel(
    const __bf16* __restrict__ qg, const __bf16* __restrict__ kg,
    const __bf16* __restrict__ vtg, const int* __restrict__ mask,
    __bf16* __restrict__ av)
{
  __shared__ __align__(16) __bf16 Ks[64 * 64];     // 8 KB
  __shared__ __align__(16) __bf16 Vt[64 * 64];     // 8 KB
  __shared__ __align__(16) __bf16 Ps[128 * 72];    // 18 KB (Q overlay at start)

  const int t = threadIdx.x, lane = t & 63, wv = t >> 6;
  const int l15 = lane & 15, q4 = lane >> 4;
  const int bh = blockIdx.x;
  const int b = bh >> 4, h = bh & (H_ - 1);
  const int q0 = blockIdx.y * 128;

  const int srow = lane & 7, sc8 = lane >> 3;
  // Q stage: wave wv covers q rows [32wv, 32wv+32), 4 passes of 8 rows, into
  // its private Ps slice (rows 32wv..32wv+32 = bytes [wv*4608, +4608) ).
  const __bf16* qg0 = qg + (size_t)(b * S_ + q0 + 32 * wv + srow) * D_ + h * DK_ + sc8 * 8;
  __bf16* lQ = Ps + wv * 2304;
#pragma unroll
  for (int p = 0; p < 4; ++p)
    ld16(qg0 + (size_t)(8 * p) * D_, lQ + 512 * p);

  // K/V staging: wave stages 16 rows of each (2 passes of 8)
  const __bf16* kg0 = kg + (size_t)(b * S_ + 16 * wv + srow) * D_ + h * DK_ + sc8 * 8;
  const __bf16* vt0 = vtg + (size_t)(bh * DK_ + 16 * wv + srow) * S_ + sc8 * 8;

  const int fb = ((l15 >> 3) << 9) + (q4 << 6) + ((l15 & 7) << 3);
  const int mrow = b * S_;

  float lsum[2] = {0.0f, 0.0f};
  f32x4 oacc[2][4];
#pragma unroll
  for (int m = 0; m < 2; ++m)
#pragma unroll
    for (int jd = 0; jd < 4; ++jd) oacc[m][jd] = (f32x4){0.f, 0.f, 0.f, 0.f};
  bf16x8 bq[2][2];

  for (int kv0 = 0; kv0 < S_; kv0 += 64) {
    ld16(kg0 + (size_t)kv0 * D_,       Ks + wv * 1024);
    ld16(kg0 + (size_t)(kv0 + 8) * D_, Ks + wv * 1024 + 512);
    ld16(vt0 + kv0,                    Vt + wv * 1024);
    ld16(vt0 + (size_t)8 * S_ + kv0,   Vt + wv * 1024 + 512);
    const int mv = mask[mrow + kv0 + lane];
    const bool dirty = (__ballot(mv == 0) != 0ull);
    __syncthreads();

    if (kv0 == 0) {   // read Q B-frags from wave-private overlay, then Ps owns it
#pragma unroll
      for (int j = 0; j < 2; ++j)
#pragma unroll
        for (int s = 0; s < 2; ++s)
          bq[j][s] = *(const bf16x8*)(lQ + j * 1024 + s * 256 + fb);
    }

    // S^T = K Q^T : rows kv (4 i-tiles), cols q (wave's 2 j-slices of 16)
    f32x4 sacc[4][2];
#pragma unroll
    for (int i = 0; i < 4; ++i)
#pragma unroll
      for (int j = 0; j < 2; ++j) sacc[i][j] = (f32x4){0.f, 0.f, 0.f, 0.f};
#pragma unroll
    for (int i = 0; i < 4; ++i)
#pragma unroll
      for (int s = 0; s < 2; ++s) {
        bf16x8 ak = *(const bf16x8*)(Ks + i * 1024 + fb + s * 256);
#pragma unroll
        for (int j = 0; j < 2; ++j)
          sacc[i][j] = __builtin_amdgcn_mfma_f32_16x16x32_bf16(ak, bq[j][s], sacc[i][j], 0, 0, 0);
      }

    if (dirty) {   // cold path (all-ones mask never takes it)
#pragma unroll
      for (int i = 0; i < 4; ++i)
#pragma unroll
        for (int r = 0; r < 4; ++r)
          if (mask[mrow + kv0 + 16 * i + 4 * q4 + r] == 0) {
            sacc[i][0][r] = -1e30f;
            sacc[i][1][r] = -1e30f;
          }
    }

    // fixed-max softmax; P -> Ps rows q (wave-local); l-sum per-lane
#pragma unroll
    for (int j = 0; j < 2; ++j) {
      float rs = 0.0f;
#pragma unroll
      for (int i = 0; i < 4; ++i) {
        bf16x4 pb;
#pragma unroll
        for (int r = 0; r < 4; ++r) {
          float pp = EXP2(sacc[i][j][r]);
          rs += pp;
          pb[r] = (__bf16)pp;
        }
        *(bf16x4*)(Ps + (wv * 32 + j * 16 + l15) * 72 + 16 * i + q4 * 4) = pb;
      }
      lsum[j] += rs;
    }

    // O += P V : A = P rows q (2 m-tiles), B = V^T rows d (4 jd-tiles)
    bf16x8 ap[2][2];
#pragma unroll
    for (int m = 0; m < 2; ++m)
#pragma unroll
      for (int s = 0; s < 2; ++s)
        ap[m][s] = *(const bf16x8*)(Ps + (wv * 32 + 16 * m + l15) * 72 + s * 32 + q4 * 8);
#pragma unroll
    for (int jd = 0; jd < 4; ++jd)
#pragma unroll
      for (int s = 0; s < 2; ++s) {
        bf16x8 bv = *(const bf16x8*)(Vt + jd * 1024 + fb + s * 256);
#pragma unroll
        for (int m = 0; m < 2; ++m)
          oacc[m][jd] = __builtin_amdgcn_mfma_f32_16x16x32_bf16(ap[m][s], bv, oacc[m][jd], 0, 0, 0);
      }
    __syncthreads();
  }

  // deferred l reduction across q4 groups, transpose to O-row ownership, store
#pragma unroll
  for (int j = 0; j < 2; ++j) {
    lsum[j] += __shfl_xor(lsum[j], 16);
    lsum[j] += __shfl_xor(lsum[j], 32);
  }
  float lt[2][4];
#pragma unroll
  for (int m = 0; m < 2; ++m)
#pragma unroll
    for (int r = 0; r < 4; ++r) lt[m][r] = 1.0f / __shfl(lsum[m], q4 * 4 + r);
#pragma unroll
  for (int m = 0; m < 2; ++m)
#pragma unroll
    for (int jd = 0; jd < 4; ++jd)
#pragma unroll
      for (int r = 0; r < 4; ++r) {
        int tok = b * S_ + q0 + wv * 32 + 16 * m + q4 * 4 + r;
        int c   = h * DK_ + jd * 16 + l15;
        av[(size_t)tok * D_ + c] = (__bf16)(oacc[m][jd][r] * lt[m][r]);
      }
}

// ---------------------------------------------------------------------------
extern "C" void kernel_launch(void* const* d_in, const int* in_sizes, int n_in,
                              void* d_out, int out_size, void* d_ws, size_t ws_size,
                              hipStream_t stream) {
  const float* x      = (const float*)d_in[0];
  const int*   mask   = (const int*)d_in[1];
  const float* wq     = (const float*)d_in[2];
  const float* wk     = (const float*)d_in[3];
  const float* wv     = (const float*)d_in[4];
  const float* wo     = (const float*)d_in[5];
  const float* w1     = (const float*)d_in[6];
  const float* b1     = (const float*)d_in[7];
  const float* w2     = (const float*)d_in[8];
  const float* b2     = (const float*)d_in[9];
  const float* alpha1 = (const float*)d_in[10];
  const float* bias1  = (const float*)d_in[11];
  const float* alpha2 = (const float*)d_in[12];
  const float* bias2  = (const float*)d_in[13];

  char* ws = (char*)d_ws;
  __bf16* wqb = (__bf16*)(ws + ((size_t)0 << 20));
  __bf16* wkb = (__bf16*)(ws + ((size_t)2 << 20));
  __bf16* wvb = (__bf16*)(ws + ((size_t)4 << 20));
  __bf16* wob = (__bf16*)(ws + ((size_t)6 << 20));
  __bf16* w1b = (__bf16*)(ws + ((size_t)8 << 20));
  __bf16* w2b = (__bf16*)(ws + ((size_t)16 << 20));
  __bf16* xn1 = (__bf16*)(ws + ((size_t)24 << 20));
  __bf16* qb  = (__bf16*)(ws + ((size_t)32 << 20));
  __bf16* kb  = (__bf16*)(ws + ((size_t)40 << 20));
  __bf16* vtb = (__bf16*)(ws + ((size_t)48 << 20));
  __bf16* avb = (__bf16*)(ws + ((size_t)56 << 20));
  float*  x1  = (float*) (ws + ((size_t)64 << 20));
  __bf16* xn2 = (__bf16*)(ws + ((size_t)56 << 20));
  __bf16* hb  = (__bf16*)(ws + ((size_t)24 << 20));
  float*  op0 = (float*) (ws + ((size_t)24 << 20));
  float*  op1 = (float*) (ws + ((size_t)40 << 20));
  __bf16* fp0 = (__bf16*)(ws + ((size_t)0 << 20));
  __bf16* fp1 = (__bf16*)(ws + ((size_t)8 << 20));

  CastJobs cj;
  cj.src[0] = wq; cj.dst[0] = wqb; cj.n4[0] = D_ * D_ / 4;
  cj.src[1] = wk; cj.dst[1] = wkb; cj.n4[1] = D_ * D_ / 4;
  cj.src[2] = wv; cj.dst[2] = wvb; cj.n4[2] = D_ * D_ / 4;
  cj.src[3] = wo; cj.dst[3] = wob; cj.n4[3] = D_ * D_ / 4;
  cj.src[4] = w1; cj.dst[4] = w1b; cj.n4[4] = DFF_ * D_ / 4;
  cj.src[5] = w2; cj.dst[5] = w2b; cj.n4[5] = DFF_ * D_ / 4;

  cast_ln_kernel<<<dim3(DFF_ * D_ / 4 / 256, 7), 256, 0, stream>>>(
      cj, x, alpha1, bias1, xn1);

  gemm_qkv<<<dim3(D_ / 128, NTOK / 128, 3), 256, 0, stream>>>(
      xn1, wqb, wkb, wvb, qb, kb, vtb);

  // BQ=128 attention: grid (bh, qtile) = (32, 16) = 512 blocks = 2/CU
  attn_kernel<<<dim3(B_ * H_, S_ / 128), 256, 0, stream>>>(qb, kb, vtb, mask, avb);

  gemm_splitk_f32<<<dim3(D_ / 128, NTOK / 128, 2), 256, 0, stream>>>(
      avb, wob, D_, D_ / 2, op0);

  oproj_ln_reduce<<<dim3(NTOK), 256, 0, stream>>>(
      x, op0, op1, alpha2, bias2, x1, xn2);

  gemm_ffn1<<<dim3(DFF_ / 128, NTOK / 128), 256, 0, stream>>>(
      xn2, w1b, hb, b1);

  gemm_splitk_bf16<<<dim3(D_ / 128, NTOK / 128, 2), 256, 0, stream>>>(
      hb, w2b, DFF_, DFF_ / 2, fp0);

  ffn2_reduce<<<dim3(NTOK * D_ / 4 / 256), 256, 0, stream>>>(
      x1, fp0, fp1, b2, (float*)d_out);
}